// Round 17
// baseline (235.859 us; speedup 1.0000x reference)
//
#include <hip/hip_runtime.h>
#include <stdint.h>

// SelfAttention N=4, L=2048, E=1024, H=16, D=64.
// Round 17: fused prep (proj | pack-v2 | cvt-v2 by block range; pack v2 is
// the efficient 16-chunks/wave version that fixed round 15's starvation).
// attn (round-12 exact, 123.6us) and out_gemm unchanged from round 16.

static constexpr int N_ = 4, L_ = 2048, E_ = 1024, H_ = 16, D_ = 64;

typedef __bf16 bf16_t;
typedef __attribute__((ext_vector_type(8))) __bf16 bf16x8;
typedef __attribute__((ext_vector_type(4))) __bf16 bf16x4;
typedef __attribute__((ext_vector_type(2))) float f32x2;
typedef __attribute__((ext_vector_type(4))) float f32x4;
typedef __attribute__((ext_vector_type(16))) float f32x16;
typedef __attribute__((ext_vector_type(4))) unsigned int uint4v;
typedef __attribute__((ext_vector_type(2))) unsigned int uint2v;

__device__ __forceinline__ f32x16 mfma32(bf16x8 a, bf16x8 b, f32x16 c) {
    return __builtin_amdgcn_mfma_f32_32x32x16_bf16(a, b, c, 0, 0, 0);
}
__device__ __forceinline__ unsigned int pk2(float a, float b) {
    union { bf16_t h[2]; unsigned int u; } z;
    z.h[0] = (bf16_t)a; z.h[1] = (bf16_t)b;
    return z.u;
}
#define GLOAD16(g, l)                                                        \
    __builtin_amdgcn_global_load_lds(                                        \
        (const __attribute__((address_space(1))) void*)(g),                  \
        (__attribute__((address_space(3))) void*)(l), 16, 0, 0)

// ---------------- fused prep: proj [0,3072) | pack [3072,7168) | cvt -------
static constexpr int PROJ_B = 3072;
static constexpr int PACK_B = 4096;

__global__ __launch_bounds__(256) void prep_k(
    const float* __restrict__ qin, const float* __restrict__ kin,
    const float* __restrict__ vin,
    const float* __restrict__ Wq, const float* __restrict__ Wk,
    const float* __restrict__ Wv,
    const int* __restrict__ mask, const float* __restrict__ Wo,
    bf16_t* __restrict__ qB, bf16_t* __restrict__ kB, bf16_t* __restrict__ vT,
    unsigned int* __restrict__ mpkT, bf16_t* __restrict__ WoB) {
    int b = blockIdx.x;
    int tid = threadIdx.x;

    if (b >= PROJ_B) {
        int pb = b - PROJ_B;
        if (pb < PACK_B) {
            // ---- mask pack v2 (identical to round-16 pack_mask_k) ----
            int wid  = pb * 4 + (tid >> 6);   // 0..16383
            int lane = tid & 63;
            int u0 = wid * 16;
            int c0 = u0 & 31;
            int q  = (u0 >> 5) & (L_ - 1);
            int n  = u0 >> 16;
            const int* src = mask + ((size_t)n * L_ + q) * L_ + c0 * 64 + lane;
            unsigned int* dst = mpkT + ((size_t)n * 64 + 2 * c0) * L_ + q;
            #pragma unroll 4
            for (int j = 0; j < 16; ++j) {
                int v = src[j * 64];
                unsigned long long bl = __ballot(v != 0);
                if (lane == 0) {
                    dst[(size_t)(2 * j) * L_]     = (unsigned int)bl;
                    dst[(size_t)(2 * j + 1) * L_] = (unsigned int)(bl >> 32);
                }
            }
        } else {
            // ---- Wo fp32 -> bf16 (float4/thread) ----
            int i = (pb - PACK_B) * 256 + tid;
            float4 f = ((const float4*)Wo)[i];
            bf16x4 o;
            o[0] = (bf16_t)f.x; o[1] = (bf16_t)f.y;
            o[2] = (bf16_t)f.z; o[3] = (bf16_t)f.w;
            ((bf16x4*)WoB)[i] = o;
        }
        return;
    }

    // ---- projection (identical to round-16 proj_mfma_k) ----
    int rem = b & 1023;
    int which = b >> 10;
    int h = (rem >> 6) & 15;
    int xb = rem & 63;
    const float* in = (which == 0) ? qin : (which == 1) ? kin : vin;
    const float* W  = (which == 0) ? Wq  : (which == 1) ? Wk  : Wv;
    int w = tid >> 6, lane = tid & 63;
    int lo5 = lane & 31, hi = lane >> 5;
    int rbase = xb * 128 + w * 32;
    int n = rbase >> 11;
    int lloc = rbase & (L_ - 1);
    int nh = n * H_ + h;

    bf16x8 xf[4];
    const float* xrow = in + (size_t)(rbase + lo5) * E_ + h * 64 + hi * 8;
    #pragma unroll
    for (int c = 0; c < 4; ++c) {
        float4 f0 = *(const float4*)(xrow + c * 16);
        float4 f1 = *(const float4*)(xrow + c * 16 + 4);
        bf16x8 v;
        v[0] = (bf16_t)f0.x; v[1] = (bf16_t)f0.y; v[2] = (bf16_t)f0.z; v[3] = (bf16_t)f0.w;
        v[4] = (bf16_t)f1.x; v[5] = (bf16_t)f1.y; v[6] = (bf16_t)f1.z; v[7] = (bf16_t)f1.w;
        xf[c] = v;
    }
    bf16x8 wf[2][4];
    #pragma unroll
    for (int t2 = 0; t2 < 2; ++t2) {
        const float* wrow = W + (size_t)(t2 * 32 + lo5) * 64 + hi * 8;
        #pragma unroll
        for (int c = 0; c < 4; ++c) {
            float4 f0 = *(const float4*)(wrow + c * 16);
            float4 f1 = *(const float4*)(wrow + c * 16 + 4);
            bf16x8 v;
            v[0] = (bf16_t)f0.x; v[1] = (bf16_t)f0.y; v[2] = (bf16_t)f0.z; v[3] = (bf16_t)f0.w;
            v[4] = (bf16_t)f1.x; v[5] = (bf16_t)f1.y; v[6] = (bf16_t)f1.z; v[7] = (bf16_t)f1.w;
            wf[t2][c] = v;
        }
    }
    f32x16 acc0, acc1;
    #pragma unroll
    for (int r = 0; r < 16; ++r) { acc0[r] = 0.f; acc1[r] = 0.f; }

    if (which != 2) {
        #pragma unroll
        for (int c = 0; c < 4; ++c) {
            acc0 = mfma32(xf[c], wf[0][c], acc0);
            acc1 = mfma32(xf[c], wf[1][c], acc1);
        }
        const float osc = (which == 0) ? (0.03125f * 1.44269504f) : 1.0f;
        bf16_t* outp = ((which == 0) ? qB : kB) + ((size_t)nh * L_ + lloc) * 64;
        #pragma unroll
        for (int r = 0; r < 16; ++r) {
            int qr = (r & 3) + 8 * (r >> 2) + 4 * hi;
            outp[qr * 64 + lo5]      = (bf16_t)(acc0[r] * osc);
            outp[qr * 64 + 32 + lo5] = (bf16_t)(acc1[r] * osc);
        }
    } else {
        #pragma unroll
        for (int c = 0; c < 4; ++c) {
            acc0 = mfma32(wf[0][c], xf[c], acc0);
            acc1 = mfma32(wf[1][c], xf[c], acc1);
        }
        bf16_t* outp = vT + (size_t)nh * 64 * L_ + lloc;
        #pragma unroll
        for (int r = 0; r < 16; ++r) {
            int dr = (r & 3) + 8 * (r >> 2) + 4 * hi;
            outp[(size_t)dr * L_ + lo5]        = (bf16_t)acc0[r];
            outp[(size_t)(dr + 32) * L_ + lo5] = (bf16_t)acc1[r];
        }
    }
}

// ---------------- attn: round-12 exact (best measured: 123.6 us) -----------
__global__ __launch_bounds__(256) void attn_lds_k(
    const bf16_t* __restrict__ qB, const bf16_t* __restrict__ kB,
    const bf16_t* __restrict__ vT, const unsigned int* __restrict__ mpkT,
    bf16_t* __restrict__ aoB) {
    __shared__ alignas(16) unsigned char smem[32768];
    int b = blockIdx.x;
    int xcd = b & 7, idx = b >> 3;
    int nh = xcd * 8 + (idx >> 4);
    int qt = idx & 15;
    int n = nh >> 4, h = nh & 15;
    int tid = threadIdx.x;
    int w = tid >> 6, lane = tid & 63;
    int lo5 = lane & 31, hi = lane >> 5;
    int q0 = qt * 128 + w * 32;

    const bf16_t* qb = qB + ((size_t)nh * L_ + q0) * D_;
    const bf16_t* kblk = kB + (size_t)nh * L_ * D_;
    const bf16_t* vblk = vT + (size_t)nh * D_ * L_;
    const unsigned int* mptr = mpkT + (size_t)n * 64 * L_ + q0 + lo5;

    int kr_ = tid >> 3, kc_ = tid & 7;
    const bf16_t* gK0 = kblk + kr_ * 64 + ((kc_ ^ (kr_ & 7)) * 8);
    const bf16_t* gK1 = gK0 + 32 * 64;
    const bf16_t* gV0 = vblk + (size_t)kr_ * L_ + ((kc_ ^ (kr_ & 7)) * 8);
    const bf16_t* gV1 = gV0 + (size_t)32 * L_;
    unsigned ldsK0 = (unsigned)(w * 1024);
    unsigned ldsK1 = (unsigned)(4096 + w * 1024);
    unsigned ldsV0 = (unsigned)(8192 + w * 1024);
    unsigned ldsV1 = (unsigned)(12288 + w * 1024);

    bf16x8 qf[4];
    #pragma unroll
    for (int c = 0; c < 4; ++c)
        qf[c] = *(const bf16x8*)(qb + lo5 * D_ + c * 16 + hi * 8);

    int kx = lo5 & 7;
    int koff0 = lo5 * 64 + (((0 | hi) ^ kx) << 3);
    int koff1 = lo5 * 64 + (((2 | hi) ^ kx) << 3);
    int koff2 = lo5 * 64 + (((4 | hi) ^ kx) << 3);
    int koff3 = lo5 * 64 + (((6 | hi) ^ kx) << 3);
    int vrow0 = 4096 + lo5 * 64;
    int vrow1 = 4096 + (lo5 + 32) * 64;
    int vb00 = ((0 | hi) ^ kx) << 3, vb01 = ((2 | hi) ^ kx) << 3;
    int vb10 = ((4 | hi) ^ kx) << 3, vb11 = ((6 | hi) ^ kx) << 3;
    int shv = hi << 2;

    f32x16 o0, o1;
    #pragma unroll
    for (int r = 0; r < 16; ++r) { o0[r] = 0.f; o1[r] = 0.f; }
    float lsum = 0.f;
    f32x16 kZero;
    #pragma unroll
    for (int r = 0; r < 16; ++r) kZero[r] = 0.f;

    auto stage = [&](int buf) {
        unsigned bb = (unsigned)buf * 16384u;
        GLOAD16(gK0, smem + bb + ldsK0);
        GLOAD16(gK1, smem + bb + ldsK1);
        GLOAD16(gV0, smem + bb + ldsV0);
        GLOAD16(gV1, smem + bb + ldsV1);
        gK0 += 64 * 64; gK1 += 64 * 64;
        gV0 += 64;      gV1 += 64;
    };

    auto sub = [&](const bf16_t* Bp, int ks, int va, int vb, unsigned int mw) {
        __builtin_amdgcn_s_setprio(1);
        f32x16 st = mfma32(*(const bf16x8*)(Bp + ks + koff0), qf[0], kZero);
        st = mfma32(*(const bf16x8*)(Bp + ks + koff1), qf[1], st);
        st = mfma32(*(const bf16x8*)(Bp + ks + koff2), qf[2], st);
        st = mfma32(*(const bf16x8*)(Bp + ks + koff3), qf[3], st);
        __builtin_amdgcn_s_setprio(0);
        bf16x8 v00 = *(const bf16x8*)(Bp + vrow0 + va);
        bf16x8 v01 = *(const bf16x8*)(Bp + vrow0 + vb);
        bf16x8 v10 = *(const bf16x8*)(Bp + vrow1 + va);
        bf16x8 v11 = *(const bf16x8*)(Bp + vrow1 + vb);
        float p[16];
        #pragma unroll
        for (int r = 0; r < 16; ++r) p[r] = __builtin_amdgcn_exp2f(st[r]);
        unsigned int mws = mw >> shv;
        #pragma unroll
        for (int r = 0; r < 16; ++r) {
            int kr = (r & 3) + 8 * (r >> 2);
            int mm = __builtin_amdgcn_sbfe(mws, kr, 1);
            p[r] = __uint_as_float(__float_as_uint(p[r]) & (unsigned int)mm);
        }
        f32x2 q01 = (f32x2){p[0], p[1]}  + (f32x2){p[2], p[3]};
        f32x2 q23 = (f32x2){p[4], p[5]}  + (f32x2){p[6], p[7]};
        f32x2 q45 = (f32x2){p[8], p[9]}  + (f32x2){p[10], p[11]};
        f32x2 q67 = (f32x2){p[12], p[13]} + (f32x2){p[14], p[15]};
        f32x2 qa = q01 + q23, qb2 = q45 + q67;
        f32x2 qc = qa + qb2;
        lsum += qc.x + qc.y;
        unsigned int w0 = pk2(p[0],  p[1]),  w1 = pk2(p[2],  p[3]);
        unsigned int w2 = pk2(p[4],  p[5]),  w3 = pk2(p[6],  p[7]);
        unsigned int w4 = pk2(p[8],  p[9]),  w5 = pk2(p[10], p[11]);
        unsigned int w6 = pk2(p[12], p[13]), w7 = pk2(p[14], p[15]);
        uint2v s02 = __builtin_amdgcn_permlane32_swap(w0, w2, false, false);
        uint2v s13 = __builtin_amdgcn_permlane32_swap(w1, w3, false, false);
        uint2v s46 = __builtin_amdgcn_permlane32_swap(w4, w6, false, false);
        uint2v s57 = __builtin_amdgcn_permlane32_swap(w5, w7, false, false);
        uint4v fa0, fa1;
        fa0.x = s02.x; fa0.y = s13.x; fa0.z = s02.y; fa0.w = s13.y;
        fa1.x = s46.x; fa1.y = s57.x; fa1.z = s46.y; fa1.w = s57.y;
        bf16x8 pa0 = __builtin_bit_cast(bf16x8, fa0);
        bf16x8 pa1 = __builtin_bit_cast(bf16x8, fa1);
        __builtin_amdgcn_s_setprio(1);
        o0 = mfma32(pa0, v00, o0);
        o1 = mfma32(pa0, v10, o1);
        o0 = mfma32(pa1, v01, o0);
        o1 = mfma32(pa1, v11, o1);
        __builtin_amdgcn_s_setprio(0);
    };

    const bf16_t* B0 = (const bf16_t*)(smem);
    const bf16_t* B1 = (const bf16_t*)(smem + 16384);

    stage(0);
    unsigned int mwa = mptr[0], mwb = mptr[L_]; mptr += 2 * L_;

    #pragma unroll 1
    for (int tt = 0; tt < 16; ++tt) {
        {
            unsigned int na = mptr[0], nb = mptr[L_]; mptr += 2 * L_;
            stage(1);
            asm volatile("s_waitcnt vmcnt(4)" ::: "memory");
            __builtin_amdgcn_s_barrier();
            __builtin_amdgcn_sched_barrier(0);
            sub(B0, 0,    vb00, vb01, mwa);
            sub(B0, 2048, vb10, vb11, mwb);
            mwa = na; mwb = nb;
            __builtin_amdgcn_s_barrier();
            __builtin_amdgcn_sched_barrier(0);
        }
        {
            unsigned int na = mptr[0], nb = mptr[L_]; mptr += 2 * L_;
            if (tt < 15) {
                stage(0);
                asm volatile("s_waitcnt vmcnt(4)" ::: "memory");
            } else {
                asm volatile("s_waitcnt vmcnt(0)" ::: "memory");
            }
            __builtin_amdgcn_s_barrier();
            __builtin_amdgcn_sched_barrier(0);
            sub(B1, 0,    vb00, vb01, mwa);
            sub(B1, 2048, vb10, vb11, mwb);
            mwa = na; mwb = nb;
            __builtin_amdgcn_s_barrier();
            __builtin_amdgcn_sched_barrier(0);
        }
    }

    float lt = lsum + __shfl_xor(lsum, 32);
    #pragma unroll
    for (int r = 0; r < 16; ++r) {
        int qr = (r & 3) + 8 * (r >> 2) + 4 * hi;
        float inv = __builtin_amdgcn_rcpf(__shfl(lt, qr));
        bf16_t* orow = aoB + ((size_t)n * L_ + q0 + qr) * E_ + h * 64;
        orow[lo5]      = (bf16_t)(o0[r] * inv);
        orow[32 + lo5] = (bf16_t)(o1[r] * inv);
    }
}

// ---------------- out GEMM: 128x128 blocks, LDS-staged Wo, dbuf ------------
__global__ __launch_bounds__(256) void out_gemm_lds_k(
    const bf16_t* __restrict__ A, const bf16_t* __restrict__ WoB,
    const float* __restrict__ bo, float* __restrict__ Y) {
    __shared__ alignas(16) unsigned char bsm[32768];   // 2 x 16KB
    int b = blockIdx.x;
    int ct = b & 7, rt = b >> 3;        // XCD-pinned column strip
    int tid = threadIdx.x;
    int w = tid >> 6, lane = tid & 63;
    int lo5 = lane & 31, hi = lane >> 5;
    int row0 = rt * 128, col0 = ct * 128;
    const bf16_t* arow = A + (size_t)(row0 + w * 32 + lo5) * E_ + hi * 8;

    f32x16 acc0, acc1, acc2, acc3;
    #pragma unroll
    for (int r = 0; r < 16; ++r) { acc0[r]=0.f; acc1[r]=0.f; acc2[r]=0.f; acc3[r]=0.f; }

    auto stageB = [&](int kc, int buf) {
        #pragma unroll
        for (int rr = 0; rr < 4; ++rr) {
            int g = tid + rr * 256;
            int nn = g >> 3, slot = g & 7;
            const bf16_t* src = WoB + (size_t)(col0 + nn) * E_ + kc * 64 +
                                ((slot ^ (nn & 7)) * 8);
            GLOAD16(src, bsm + (size_t)buf * 16384 + (size_t)(w * 64 + rr * 256) * 16);
        }
    };

    stageB(0, 0);
    #pragma unroll 1
    for (int kc = 0; kc < 16; ++kc) {
        int cur = kc & 1;
        if (kc < 15) stageB(kc + 1, cur ^ 1);
        if (kc < 15) { asm volatile("s_waitcnt vmcnt(4)" ::: "memory"); }
        else         { asm volatile("s_waitcnt vmcnt(0)" ::: "memory"); }
        __builtin_amdgcn_s_barrier();
        __builtin_amdgcn_sched_barrier(0);
        const bf16_t* Bl = (const bf16_t*)(bsm + (size_t)cur * 16384);
        #pragma unroll
        for (int c = 0; c < 4; ++c) {
            bf16x8 af = *(const bf16x8*)(arow + kc * 64 + c * 16);
            int slot = ((((c << 1) | hi) ^ (lo5 & 7)) << 3);
            bf16x8 b0 = *(const bf16x8*)(Bl + (0 * 32 + lo5) * 64 + slot);
            bf16x8 b1 = *(const bf16x8*)(Bl + (1 * 32 + lo5) * 64 + slot);
            bf16x8 b2 = *(const bf16x8*)(Bl + (2 * 32 + lo5) * 64 + slot);
            bf16x8 b3 = *(const bf16x8*)(Bl + (3 * 32 + lo5) * 64 + slot);
            __builtin_amdgcn_s_setprio(1);
            acc0 = mfma32(af, b0, acc0);
            acc1 = mfma32(af, b1, acc1);
            acc2 = mfma32(af, b2, acc2);
            acc3 = mfma32(af, b3, acc3);
            __builtin_amdgcn_s_setprio(0);
        }
        __builtin_amdgcn_s_barrier();
        __builtin_amdgcn_sched_barrier(0);
    }

    #define EPI(ACC, CG)                                                     \
    {                                                                        \
        float bias = bo[col0 + (CG) * 32 + lo5];                             \
        _Pragma("unroll")                                                    \
        for (int r = 0; r < 16; ++r) {                                       \
            int qr = (r & 3) + 8 * (r >> 2) + 4 * hi;                        \
            Y[(size_t)(row0 + w * 32 + qr) * E_ + col0 + (CG) * 32 + lo5] =  \
                ACC[r] + bias;                                               \
        }                                                                    \
    }
    EPI(acc0, 0) EPI(acc1, 1) EPI(acc2, 2) EPI(acc3, 3)
    #undef EPI
}

extern "C" void kernel_launch(void* const* d_in, const int* in_sizes, int n_in,
                              void* d_out, int out_size, void* d_ws, size_t ws_size,
                              hipStream_t stream) {
    const float* values  = (const float*)d_in[0];
    const float* keys    = (const float*)d_in[1];
    const float* queries = (const float*)d_in[2];
    const int*   mask    = (const int*)  d_in[3];
    const float* Wq      = (const float*)d_in[4];
    const float* Wk      = (const float*)d_in[5];
    const float* Wv      = (const float*)d_in[6];
    const float* Wo      = (const float*)d_in[7];
    const float* bo      = (const float*)d_in[8];
    float* Y = (float*)d_out;

    const size_t SZ = (size_t)N_ * H_ * L_ * D_;  // 8388608 elements
    bf16_t* qB  = (bf16_t*)d_ws;
    bf16_t* kB  = qB + SZ;
    bf16_t* vT  = kB + SZ;
    bf16_t* aoB = vT + SZ;
    unsigned int* mpkT = (unsigned int*)(aoB + SZ);
    bf16_t* WoB = (bf16_t*)(mpkT + (size_t)N_ * 64 * L_);

    prep_k<<<PROJ_B + PACK_B + 1024, 256, 0, stream>>>(
        queries, keys, values, Wq, Wk, Wv, mask, Wo,
        qB, kB, vT, mpkT, WoB);
    attn_lds_k<<<N_ * H_ * (L_ / 128), 256, 0, stream>>>(
        qB, kB, vT, mpkT, aoB);
    out_gemm_lds_k<<<(E_ / 128) * (N_ * L_ / 128), 256, 0, stream>>>(
        aoB, WoB, bo, Y);
}

// Round 18
// 203.352 us; speedup vs baseline: 1.1599x; 1.1599x over previous
//
#include <hip/hip_runtime.h>
#include <stdint.h>

// SelfAttention N=4, L=2048, E=1024, H=16, D=64.
// Round 18: round-16 serial structure (best, 215.7us) + out_gemm A-prefetch
// (counted vmcnt(8)) + pack/cvt merged into one launch. attn/proj identical
// to round 16.

static constexpr int N_ = 4, L_ = 2048, E_ = 1024, H_ = 16, D_ = 64;

typedef __bf16 bf16_t;
typedef __attribute__((ext_vector_type(8))) __bf16 bf16x8;
typedef __attribute__((ext_vector_type(4))) __bf16 bf16x4;
typedef __attribute__((ext_vector_type(2))) float f32x2;
typedef __attribute__((ext_vector_type(4))) float f32x4;
typedef __attribute__((ext_vector_type(16))) float f32x16;
typedef __attribute__((ext_vector_type(4))) unsigned int uint4v;
typedef __attribute__((ext_vector_type(2))) unsigned int uint2v;

__device__ __forceinline__ f32x16 mfma32(bf16x8 a, bf16x8 b, f32x16 c) {
    return __builtin_amdgcn_mfma_f32_32x32x16_bf16(a, b, c, 0, 0, 0);
}
__device__ __forceinline__ unsigned int pk2(float a, float b) {
    union { bf16_t h[2]; unsigned int u; } z;
    z.h[0] = (bf16_t)a; z.h[1] = (bf16_t)b;
    return z.u;
}
#define GLOAD16(g, l)                                                        \
    __builtin_amdgcn_global_load_lds(                                        \
        (const __attribute__((address_space(1))) void*)(g),                  \
        (__attribute__((address_space(3))) void*)(l), 16, 0, 0)

// ---------------- pack (blocks 0..4095) + cvt (4096..5119), one launch -----
__global__ __launch_bounds__(256) void pack_cvt_k(
    const int* __restrict__ mask, const float* __restrict__ Wo,
    unsigned int* __restrict__ mpkT, bf16_t* __restrict__ WoB) {
    int b = blockIdx.x;
    int tid = threadIdx.x;
    if (b < 4096) {
        int wid  = b * 4 + (tid >> 6);   // 0..16383
        int lane = tid & 63;
        int u0 = wid * 16;
        int c0 = u0 & 31;
        int q  = (u0 >> 5) & (L_ - 1);
        int n  = u0 >> 16;
        const int* src = mask + ((size_t)n * L_ + q) * L_ + c0 * 64 + lane;
        unsigned int* dst = mpkT + ((size_t)n * 64 + 2 * c0) * L_ + q;
        #pragma unroll 4
        for (int j = 0; j < 16; ++j) {
            int v = src[j * 64];
            unsigned long long bl = __ballot(v != 0);
            if (lane == 0) {
                dst[(size_t)(2 * j) * L_]     = (unsigned int)bl;
                dst[(size_t)(2 * j + 1) * L_] = (unsigned int)(bl >> 32);
            }
        }
    } else {
        int i = (b - 4096) * 256 + tid;
        float4 f = ((const float4*)Wo)[i];
        bf16x4 o;
        o[0] = (bf16_t)f.x; o[1] = (bf16_t)f.y;
        o[2] = (bf16_t)f.z; o[3] = (bf16_t)f.w;
        ((bf16x4*)WoB)[i] = o;
    }
}

// ---------------- MFMA projection (csc folded into Q output) ---------------
__global__ __launch_bounds__(256) void proj_mfma_k(
    const float* __restrict__ qin, const float* __restrict__ kin,
    const float* __restrict__ vin,
    const float* __restrict__ Wq, const float* __restrict__ Wk,
    const float* __restrict__ Wv,
    bf16_t* __restrict__ qB, bf16_t* __restrict__ kB, bf16_t* __restrict__ vT) {
    int which = blockIdx.z;
    int h = blockIdx.y;
    const float* in = (which == 0) ? qin : (which == 1) ? kin : vin;
    const float* W  = (which == 0) ? Wq  : (which == 1) ? Wk  : Wv;
    int w = threadIdx.x >> 6, lane = threadIdx.x & 63;
    int lo5 = lane & 31, hi = lane >> 5;
    int rbase = blockIdx.x * 128 + w * 32;
    int n = rbase >> 11;
    int lloc = rbase & (L_ - 1);
    int nh = n * H_ + h;

    bf16x8 xf[4];
    const float* xrow = in + (size_t)(rbase + lo5) * E_ + h * 64 + hi * 8;
    #pragma unroll
    for (int c = 0; c < 4; ++c) {
        float4 f0 = *(const float4*)(xrow + c * 16);
        float4 f1 = *(const float4*)(xrow + c * 16 + 4);
        bf16x8 v;
        v[0] = (bf16_t)f0.x; v[1] = (bf16_t)f0.y; v[2] = (bf16_t)f0.z; v[3] = (bf16_t)f0.w;
        v[4] = (bf16_t)f1.x; v[5] = (bf16_t)f1.y; v[6] = (bf16_t)f1.z; v[7] = (bf16_t)f1.w;
        xf[c] = v;
    }
    bf16x8 wf[2][4];
    #pragma unroll
    for (int t2 = 0; t2 < 2; ++t2) {
        const float* wrow = W + (size_t)(t2 * 32 + lo5) * 64 + hi * 8;
        #pragma unroll
        for (int c = 0; c < 4; ++c) {
            float4 f0 = *(const float4*)(wrow + c * 16);
            float4 f1 = *(const float4*)(wrow + c * 16 + 4);
            bf16x8 v;
            v[0] = (bf16_t)f0.x; v[1] = (bf16_t)f0.y; v[2] = (bf16_t)f0.z; v[3] = (bf16_t)f0.w;
            v[4] = (bf16_t)f1.x; v[5] = (bf16_t)f1.y; v[6] = (bf16_t)f1.z; v[7] = (bf16_t)f1.w;
            wf[t2][c] = v;
        }
    }
    f32x16 acc0, acc1;
    #pragma unroll
    for (int r = 0; r < 16; ++r) { acc0[r] = 0.f; acc1[r] = 0.f; }

    if (which != 2) {
        #pragma unroll
        for (int c = 0; c < 4; ++c) {
            acc0 = mfma32(xf[c], wf[0][c], acc0);
            acc1 = mfma32(xf[c], wf[1][c], acc1);
        }
        const float osc = (which == 0) ? (0.03125f * 1.44269504f) : 1.0f;
        bf16_t* outp = ((which == 0) ? qB : kB) + ((size_t)nh * L_ + lloc) * 64;
        #pragma unroll
        for (int r = 0; r < 16; ++r) {
            int qr = (r & 3) + 8 * (r >> 2) + 4 * hi;
            outp[qr * 64 + lo5]      = (bf16_t)(acc0[r] * osc);
            outp[qr * 64 + 32 + lo5] = (bf16_t)(acc1[r] * osc);
        }
    } else {
        #pragma unroll
        for (int c = 0; c < 4; ++c) {
            acc0 = mfma32(wf[0][c], xf[c], acc0);
            acc1 = mfma32(wf[1][c], xf[c], acc1);
        }
        bf16_t* outp = vT + (size_t)nh * 64 * L_ + lloc;
        #pragma unroll
        for (int r = 0; r < 16; ++r) {
            int dr = (r & 3) + 8 * (r >> 2) + 4 * hi;
            outp[(size_t)dr * L_ + lo5]        = (bf16_t)acc0[r];
            outp[(size_t)(dr + 32) * L_ + lo5] = (bf16_t)acc1[r];
        }
    }
}

// ---------------- attn: round-12 exact (best measured: 123.6 us) -----------
__global__ __launch_bounds__(256) void attn_lds_k(
    const bf16_t* __restrict__ qB, const bf16_t* __restrict__ kB,
    const bf16_t* __restrict__ vT, const unsigned int* __restrict__ mpkT,
    bf16_t* __restrict__ aoB) {
    __shared__ alignas(16) unsigned char smem[32768];
    int b = blockIdx.x;
    int xcd = b & 7, idx = b >> 3;
    int nh = xcd * 8 + (idx >> 4);
    int qt = idx & 15;
    int n = nh >> 4, h = nh & 15;
    int tid = threadIdx.x;
    int w = tid >> 6, lane = tid & 63;
    int lo5 = lane & 31, hi = lane >> 5;
    int q0 = qt * 128 + w * 32;

    const bf16_t* qb = qB + ((size_t)nh * L_ + q0) * D_;
    const bf16_t* kblk = kB + (size_t)nh * L_ * D_;
    const bf16_t* vblk = vT + (size_t)nh * D_ * L_;
    const unsigned int* mptr = mpkT + (size_t)n * 64 * L_ + q0 + lo5;

    int kr_ = tid >> 3, kc_ = tid & 7;
    const bf16_t* gK0 = kblk + kr_ * 64 + ((kc_ ^ (kr_ & 7)) * 8);
    const bf16_t* gK1 = gK0 + 32 * 64;
    const bf16_t* gV0 = vblk + (size_t)kr_ * L_ + ((kc_ ^ (kr_ & 7)) * 8);
    const bf16_t* gV1 = gV0 + (size_t)32 * L_;
    unsigned ldsK0 = (unsigned)(w * 1024);
    unsigned ldsK1 = (unsigned)(4096 + w * 1024);
    unsigned ldsV0 = (unsigned)(8192 + w * 1024);
    unsigned ldsV1 = (unsigned)(12288 + w * 1024);

    bf16x8 qf[4];
    #pragma unroll
    for (int c = 0; c < 4; ++c)
        qf[c] = *(const bf16x8*)(qb + lo5 * D_ + c * 16 + hi * 8);

    int kx = lo5 & 7;
    int koff0 = lo5 * 64 + (((0 | hi) ^ kx) << 3);
    int koff1 = lo5 * 64 + (((2 | hi) ^ kx) << 3);
    int koff2 = lo5 * 64 + (((4 | hi) ^ kx) << 3);
    int koff3 = lo5 * 64 + (((6 | hi) ^ kx) << 3);
    int vrow0 = 4096 + lo5 * 64;
    int vrow1 = 4096 + (lo5 + 32) * 64;
    int vb00 = ((0 | hi) ^ kx) << 3, vb01 = ((2 | hi) ^ kx) << 3;
    int vb10 = ((4 | hi) ^ kx) << 3, vb11 = ((6 | hi) ^ kx) << 3;
    int shv = hi << 2;

    f32x16 o0, o1;
    #pragma unroll
    for (int r = 0; r < 16; ++r) { o0[r] = 0.f; o1[r] = 0.f; }
    float lsum = 0.f;
    f32x16 kZero;
    #pragma unroll
    for (int r = 0; r < 16; ++r) kZero[r] = 0.f;

    auto stage = [&](int buf) {
        unsigned bb = (unsigned)buf * 16384u;
        GLOAD16(gK0, smem + bb + ldsK0);
        GLOAD16(gK1, smem + bb + ldsK1);
        GLOAD16(gV0, smem + bb + ldsV0);
        GLOAD16(gV1, smem + bb + ldsV1);
        gK0 += 64 * 64; gK1 += 64 * 64;
        gV0 += 64;      gV1 += 64;
    };

    auto sub = [&](const bf16_t* Bp, int ks, int va, int vb, unsigned int mw) {
        __builtin_amdgcn_s_setprio(1);
        f32x16 st = mfma32(*(const bf16x8*)(Bp + ks + koff0), qf[0], kZero);
        st = mfma32(*(const bf16x8*)(Bp + ks + koff1), qf[1], st);
        st = mfma32(*(const bf16x8*)(Bp + ks + koff2), qf[2], st);
        st = mfma32(*(const bf16x8*)(Bp + ks + koff3), qf[3], st);
        __builtin_amdgcn_s_setprio(0);
        bf16x8 v00 = *(const bf16x8*)(Bp + vrow0 + va);
        bf16x8 v01 = *(const bf16x8*)(Bp + vrow0 + vb);
        bf16x8 v10 = *(const bf16x8*)(Bp + vrow1 + va);
        bf16x8 v11 = *(const bf16x8*)(Bp + vrow1 + vb);
        float p[16];
        #pragma unroll
        for (int r = 0; r < 16; ++r) p[r] = __builtin_amdgcn_exp2f(st[r]);
        unsigned int mws = mw >> shv;
        #pragma unroll
        for (int r = 0; r < 16; ++r) {
            int kr = (r & 3) + 8 * (r >> 2);
            int mm = __builtin_amdgcn_sbfe(mws, kr, 1);
            p[r] = __uint_as_float(__float_as_uint(p[r]) & (unsigned int)mm);
        }
        f32x2 q01 = (f32x2){p[0], p[1]}  + (f32x2){p[2], p[3]};
        f32x2 q23 = (f32x2){p[4], p[5]}  + (f32x2){p[6], p[7]};
        f32x2 q45 = (f32x2){p[8], p[9]}  + (f32x2){p[10], p[11]};
        f32x2 q67 = (f32x2){p[12], p[13]} + (f32x2){p[14], p[15]};
        f32x2 qa = q01 + q23, qb2 = q45 + q67;
        f32x2 qc = qa + qb2;
        lsum += qc.x + qc.y;
        unsigned int w0 = pk2(p[0],  p[1]),  w1 = pk2(p[2],  p[3]);
        unsigned int w2 = pk2(p[4],  p[5]),  w3 = pk2(p[6],  p[7]);
        unsigned int w4 = pk2(p[8],  p[9]),  w5 = pk2(p[10], p[11]);
        unsigned int w6 = pk2(p[12], p[13]), w7 = pk2(p[14], p[15]);
        uint2v s02 = __builtin_amdgcn_permlane32_swap(w0, w2, false, false);
        uint2v s13 = __builtin_amdgcn_permlane32_swap(w1, w3, false, false);
        uint2v s46 = __builtin_amdgcn_permlane32_swap(w4, w6, false, false);
        uint2v s57 = __builtin_amdgcn_permlane32_swap(w5, w7, false, false);
        uint4v fa0, fa1;
        fa0.x = s02.x; fa0.y = s13.x; fa0.z = s02.y; fa0.w = s13.y;
        fa1.x = s46.x; fa1.y = s57.x; fa1.z = s46.y; fa1.w = s57.y;
        bf16x8 pa0 = __builtin_bit_cast(bf16x8, fa0);
        bf16x8 pa1 = __builtin_bit_cast(bf16x8, fa1);
        __builtin_amdgcn_s_setprio(1);
        o0 = mfma32(pa0, v00, o0);
        o1 = mfma32(pa0, v10, o1);
        o0 = mfma32(pa1, v01, o0);
        o1 = mfma32(pa1, v11, o1);
        __builtin_amdgcn_s_setprio(0);
    };

    const bf16_t* B0 = (const bf16_t*)(smem);
    const bf16_t* B1 = (const bf16_t*)(smem + 16384);

    stage(0);
    unsigned int mwa = mptr[0], mwb = mptr[L_]; mptr += 2 * L_;

    #pragma unroll 1
    for (int tt = 0; tt < 16; ++tt) {
        {
            unsigned int na = mptr[0], nb = mptr[L_]; mptr += 2 * L_;
            stage(1);
            asm volatile("s_waitcnt vmcnt(4)" ::: "memory");
            __builtin_amdgcn_s_barrier();
            __builtin_amdgcn_sched_barrier(0);
            sub(B0, 0,    vb00, vb01, mwa);
            sub(B0, 2048, vb10, vb11, mwb);
            mwa = na; mwb = nb;
            __builtin_amdgcn_s_barrier();
            __builtin_amdgcn_sched_barrier(0);
        }
        {
            unsigned int na = mptr[0], nb = mptr[L_]; mptr += 2 * L_;
            if (tt < 15) {
                stage(0);
                asm volatile("s_waitcnt vmcnt(4)" ::: "memory");
            } else {
                asm volatile("s_waitcnt vmcnt(0)" ::: "memory");
            }
            __builtin_amdgcn_s_barrier();
            __builtin_amdgcn_sched_barrier(0);
            sub(B1, 0,    vb00, vb01, mwa);
            sub(B1, 2048, vb10, vb11, mwb);
            mwa = na; mwb = nb;
            __builtin_amdgcn_s_barrier();
            __builtin_amdgcn_sched_barrier(0);
        }
    }

    float lt = lsum + __shfl_xor(lsum, 32);
    #pragma unroll
    for (int r = 0; r < 16; ++r) {
        int qr = (r & 3) + 8 * (r >> 2) + 4 * hi;
        float inv = __builtin_amdgcn_rcpf(__shfl(lt, qr));
        bf16_t* orow = aoB + ((size_t)n * L_ + q0 + qr) * E_ + h * 64;
        orow[lo5]      = (bf16_t)(o0[r] * inv);
        orow[32 + lo5] = (bf16_t)(o1[r] * inv);
    }
}

// ---------------- out GEMM: 128x128, LDS Wo dbuf + A reg-prefetch ----------
__global__ __launch_bounds__(256) void out_gemm_lds_k(
    const bf16_t* __restrict__ A, const bf16_t* __restrict__ WoB,
    const float* __restrict__ bo, float* __restrict__ Y) {
    __shared__ alignas(16) unsigned char bsm[32768];   // 2 x 16KB
    int b = blockIdx.x;
    int ct = b & 7, rt = b >> 3;        // XCD-pinned column strip
    int tid = threadIdx.x;
    int w = tid >> 6, lane = tid & 63;
    int lo5 = lane & 31, hi = lane >> 5;
    int row0 = rt * 128, col0 = ct * 128;
    const bf16_t* arow = A + (size_t)(row0 + w * 32 + lo5) * E_ + hi * 8;

    f32x16 acc0, acc1, acc2, acc3;
    #pragma unroll
    for (int r = 0; r < 16; ++r) { acc0[r]=0.f; acc1[r]=0.f; acc2[r]=0.f; acc3[r]=0.f; }

    auto stageB = [&](int kc, int buf) {
        #pragma unroll
        for (int rr = 0; rr < 4; ++rr) {
            int g = tid + rr * 256;
            int nn = g >> 3, slot = g & 7;
            const bf16_t* src = WoB + (size_t)(col0 + nn) * E_ + kc * 64 +
                                ((slot ^ (nn & 7)) * 8);
            GLOAD16(src, bsm + (size_t)buf * 16384 + (size_t)(w * 64 + rr * 256) * 16);
        }
    };

    // prologue: stage Wo tile 0, prefetch A frags for kc=0
    stageB(0, 0);
    bf16x8 afc[4];
    #pragma unroll
    for (int c = 0; c < 4; ++c) afc[c] = *(const bf16x8*)(arow + c * 16);

    #pragma unroll 1
    for (int kc = 0; kc < 16; ++kc) {
        int cur = kc & 1;
        bf16x8 afn[4];
        if (kc < 15) {
            stageB(kc + 1, cur ^ 1);
            #pragma unroll
            for (int c = 0; c < 4; ++c)
                afn[c] = *(const bf16x8*)(arow + (kc + 1) * 64 + c * 16);
            asm volatile("s_waitcnt vmcnt(8)" ::: "memory");
        } else {
            asm volatile("s_waitcnt vmcnt(0)" ::: "memory");
        }
        __builtin_amdgcn_s_barrier();
        __builtin_amdgcn_sched_barrier(0);
        const bf16_t* Bl = (const bf16_t*)(bsm + (size_t)cur * 16384);
        #pragma unroll
        for (int c = 0; c < 4; ++c) {
            int slot = ((((c << 1) | hi) ^ (lo5 & 7)) << 3);
            bf16x8 b0 = *(const bf16x8*)(Bl + (0 * 32 + lo5) * 64 + slot);
            bf16x8 b1 = *(const bf16x8*)(Bl + (1 * 32 + lo5) * 64 + slot);
            bf16x8 b2 = *(const bf16x8*)(Bl + (2 * 32 + lo5) * 64 + slot);
            bf16x8 b3 = *(const bf16x8*)(Bl + (3 * 32 + lo5) * 64 + slot);
            __builtin_amdgcn_s_setprio(1);
            acc0 = mfma32(afc[c], b0, acc0);
            acc1 = mfma32(afc[c], b1, acc1);
            acc2 = mfma32(afc[c], b2, acc2);
            acc3 = mfma32(afc[c], b3, acc3);
            __builtin_amdgcn_s_setprio(0);
        }
        #pragma unroll
        for (int c = 0; c < 4; ++c) afc[c] = afn[c];
        __builtin_amdgcn_s_barrier();
        __builtin_amdgcn_sched_barrier(0);
    }

    #define EPI(ACC, CG)                                                     \
    {                                                                        \
        float bias = bo[col0 + (CG) * 32 + lo5];                             \
        _Pragma("unroll")                                                    \
        for (int r = 0; r < 16; ++r) {                                       \
            int qr = (r & 3) + 8 * (r >> 2) + 4 * hi;                        \
            Y[(size_t)(row0 + w * 32 + qr) * E_ + col0 + (CG) * 32 + lo5] =  \
                ACC[r] + bias;                                               \
        }                                                                    \
    }
    EPI(acc0, 0) EPI(acc1, 1) EPI(acc2, 2) EPI(acc3, 3)
    #undef EPI
}

extern "C" void kernel_launch(void* const* d_in, const int* in_sizes, int n_in,
                              void* d_out, int out_size, void* d_ws, size_t ws_size,
                              hipStream_t stream) {
    const float* values  = (const float*)d_in[0];
    const float* keys    = (const float*)d_in[1];
    const float* queries = (const float*)d_in[2];
    const int*   mask    = (const int*)  d_in[3];
    const float* Wq      = (const float*)d_in[4];
    const float* Wk      = (const float*)d_in[5];
    const float* Wv      = (const float*)d_in[6];
    const float* Wo      = (const float*)d_in[7];
    const float* bo      = (const float*)d_in[8];
    float* Y = (float*)d_out;

    const size_t SZ = (size_t)N_ * H_ * L_ * D_;  // 8388608 elements
    bf16_t* qB  = (bf16_t*)d_ws;
    bf16_t* kB  = qB + SZ;
    bf16_t* vT  = kB + SZ;
    bf16_t* aoB = vT + SZ;
    unsigned int* mpkT = (unsigned int*)(aoB + SZ);
    bf16_t* WoB = (bf16_t*)(mpkT + (size_t)N_ * 64 * L_);

    pack_cvt_k<<<4096 + 1024, 256, 0, stream>>>(mask, Wo, mpkT, WoB);
    proj_mfma_k<<<dim3(N_ * L_ / 128, H_, 3), 256, 0, stream>>>(
        queries, keys, values, Wq, Wk, Wv, qB, kB, vT);
    attn_lds_k<<<N_ * H_ * (L_ / 128), 256, 0, stream>>>(
        qB, kB, vT, mpkT, aoB);
    out_gemm_lds_k<<<(E_ / 128) * (N_ * L_ / 128), 256, 0, stream>>>(
        aoB, WoB, bo, Y);
}

// Round 19
// 203.216 us; speedup vs baseline: 1.1606x; 1.0007x over previous
//
#include <hip/hip_runtime.h>
#include <stdint.h>

// SelfAttention N=4, L=2048, E=1024, H=16, D=64.
// Round 19: out_gemm block remap — XCD owns a ROW-group (A panel 2MB L2-
// resident) and iterates all Wo column strips (2MB, also L2-resident);
// replaces the old col-strip pinning where A streamed 8x from L3.
// Everything else byte-identical to round 18 (best, 203.4us).

static constexpr int N_ = 4, L_ = 2048, E_ = 1024, H_ = 16, D_ = 64;

typedef __bf16 bf16_t;
typedef __attribute__((ext_vector_type(8))) __bf16 bf16x8;
typedef __attribute__((ext_vector_type(4))) __bf16 bf16x4;
typedef __attribute__((ext_vector_type(2))) float f32x2;
typedef __attribute__((ext_vector_type(4))) float f32x4;
typedef __attribute__((ext_vector_type(16))) float f32x16;
typedef __attribute__((ext_vector_type(4))) unsigned int uint4v;
typedef __attribute__((ext_vector_type(2))) unsigned int uint2v;

__device__ __forceinline__ f32x16 mfma32(bf16x8 a, bf16x8 b, f32x16 c) {
    return __builtin_amdgcn_mfma_f32_32x32x16_bf16(a, b, c, 0, 0, 0);
}
__device__ __forceinline__ unsigned int pk2(float a, float b) {
    union { bf16_t h[2]; unsigned int u; } z;
    z.h[0] = (bf16_t)a; z.h[1] = (bf16_t)b;
    return z.u;
}
#define GLOAD16(g, l)                                                        \
    __builtin_amdgcn_global_load_lds(                                        \
        (const __attribute__((address_space(1))) void*)(g),                  \
        (__attribute__((address_space(3))) void*)(l), 16, 0, 0)

// ---------------- pack (blocks 0..4095) + cvt (4096..5119), one launch -----
__global__ __launch_bounds__(256) void pack_cvt_k(
    const int* __restrict__ mask, const float* __restrict__ Wo,
    unsigned int* __restrict__ mpkT, bf16_t* __restrict__ WoB) {
    int b = blockIdx.x;
    int tid = threadIdx.x;
    if (b < 4096) {
        int wid  = b * 4 + (tid >> 6);   // 0..16383
        int lane = tid & 63;
        int u0 = wid * 16;
        int c0 = u0 & 31;
        int q  = (u0 >> 5) & (L_ - 1);
        int n  = u0 >> 16;
        const int* src = mask + ((size_t)n * L_ + q) * L_ + c0 * 64 + lane;
        unsigned int* dst = mpkT + ((size_t)n * 64 + 2 * c0) * L_ + q;
        #pragma unroll 4
        for (int j = 0; j < 16; ++j) {
            int v = src[j * 64];
            unsigned long long bl = __ballot(v != 0);
            if (lane == 0) {
                dst[(size_t)(2 * j) * L_]     = (unsigned int)bl;
                dst[(size_t)(2 * j + 1) * L_] = (unsigned int)(bl >> 32);
            }
        }
    } else {
        int i = (b - 4096) * 256 + tid;
        float4 f = ((const float4*)Wo)[i];
        bf16x4 o;
        o[0] = (bf16_t)f.x; o[1] = (bf16_t)f.y;
        o[2] = (bf16_t)f.z; o[3] = (bf16_t)f.w;
        ((bf16x4*)WoB)[i] = o;
    }
}

// ---------------- MFMA projection (csc folded into Q output) ---------------
__global__ __launch_bounds__(256) void proj_mfma_k(
    const float* __restrict__ qin, const float* __restrict__ kin,
    const float* __restrict__ vin,
    const float* __restrict__ Wq, const float* __restrict__ Wk,
    const float* __restrict__ Wv,
    bf16_t* __restrict__ qB, bf16_t* __restrict__ kB, bf16_t* __restrict__ vT) {
    int which = blockIdx.z;
    int h = blockIdx.y;
    const float* in = (which == 0) ? qin : (which == 1) ? kin : vin;
    const float* W  = (which == 0) ? Wq  : (which == 1) ? Wk  : Wv;
    int w = threadIdx.x >> 6, lane = threadIdx.x & 63;
    int lo5 = lane & 31, hi = lane >> 5;
    int rbase = blockIdx.x * 128 + w * 32;
    int n = rbase >> 11;
    int lloc = rbase & (L_ - 1);
    int nh = n * H_ + h;

    bf16x8 xf[4];
    const float* xrow = in + (size_t)(rbase + lo5) * E_ + h * 64 + hi * 8;
    #pragma unroll
    for (int c = 0; c < 4; ++c) {
        float4 f0 = *(const float4*)(xrow + c * 16);
        float4 f1 = *(const float4*)(xrow + c * 16 + 4);
        bf16x8 v;
        v[0] = (bf16_t)f0.x; v[1] = (bf16_t)f0.y; v[2] = (bf16_t)f0.z; v[3] = (bf16_t)f0.w;
        v[4] = (bf16_t)f1.x; v[5] = (bf16_t)f1.y; v[6] = (bf16_t)f1.z; v[7] = (bf16_t)f1.w;
        xf[c] = v;
    }
    bf16x8 wf[2][4];
    #pragma unroll
    for (int t2 = 0; t2 < 2; ++t2) {
        const float* wrow = W + (size_t)(t2 * 32 + lo5) * 64 + hi * 8;
        #pragma unroll
        for (int c = 0; c < 4; ++c) {
            float4 f0 = *(const float4*)(wrow + c * 16);
            float4 f1 = *(const float4*)(wrow + c * 16 + 4);
            bf16x8 v;
            v[0] = (bf16_t)f0.x; v[1] = (bf16_t)f0.y; v[2] = (bf16_t)f0.z; v[3] = (bf16_t)f0.w;
            v[4] = (bf16_t)f1.x; v[5] = (bf16_t)f1.y; v[6] = (bf16_t)f1.z; v[7] = (bf16_t)f1.w;
            wf[t2][c] = v;
        }
    }
    f32x16 acc0, acc1;
    #pragma unroll
    for (int r = 0; r < 16; ++r) { acc0[r] = 0.f; acc1[r] = 0.f; }

    if (which != 2) {
        #pragma unroll
        for (int c = 0; c < 4; ++c) {
            acc0 = mfma32(xf[c], wf[0][c], acc0);
            acc1 = mfma32(xf[c], wf[1][c], acc1);
        }
        const float osc = (which == 0) ? (0.03125f * 1.44269504f) : 1.0f;
        bf16_t* outp = ((which == 0) ? qB : kB) + ((size_t)nh * L_ + lloc) * 64;
        #pragma unroll
        for (int r = 0; r < 16; ++r) {
            int qr = (r & 3) + 8 * (r >> 2) + 4 * hi;
            outp[qr * 64 + lo5]      = (bf16_t)(acc0[r] * osc);
            outp[qr * 64 + 32 + lo5] = (bf16_t)(acc1[r] * osc);
        }
    } else {
        #pragma unroll
        for (int c = 0; c < 4; ++c) {
            acc0 = mfma32(wf[0][c], xf[c], acc0);
            acc1 = mfma32(wf[1][c], xf[c], acc1);
        }
        bf16_t* outp = vT + (size_t)nh * 64 * L_ + lloc;
        #pragma unroll
        for (int r = 0; r < 16; ++r) {
            int dr = (r & 3) + 8 * (r >> 2) + 4 * hi;
            outp[(size_t)dr * L_ + lo5]        = (bf16_t)acc0[r];
            outp[(size_t)(dr + 32) * L_ + lo5] = (bf16_t)acc1[r];
        }
    }
}

// ---------------- attn: round-12 exact (best measured: 123.6 us) -----------
__global__ __launch_bounds__(256) void attn_lds_k(
    const bf16_t* __restrict__ qB, const bf16_t* __restrict__ kB,
    const bf16_t* __restrict__ vT, const unsigned int* __restrict__ mpkT,
    bf16_t* __restrict__ aoB) {
    __shared__ alignas(16) unsigned char smem[32768];
    int b = blockIdx.x;
    int xcd = b & 7, idx = b >> 3;
    int nh = xcd * 8 + (idx >> 4);
    int qt = idx & 15;
    int n = nh >> 4, h = nh & 15;
    int tid = threadIdx.x;
    int w = tid >> 6, lane = tid & 63;
    int lo5 = lane & 31, hi = lane >> 5;
    int q0 = qt * 128 + w * 32;

    const bf16_t* qb = qB + ((size_t)nh * L_ + q0) * D_;
    const bf16_t* kblk = kB + (size_t)nh * L_ * D_;
    const bf16_t* vblk = vT + (size_t)nh * D_ * L_;
    const unsigned int* mptr = mpkT + (size_t)n * 64 * L_ + q0 + lo5;

    int kr_ = tid >> 3, kc_ = tid & 7;
    const bf16_t* gK0 = kblk + kr_ * 64 + ((kc_ ^ (kr_ & 7)) * 8);
    const bf16_t* gK1 = gK0 + 32 * 64;
    const bf16_t* gV0 = vblk + (size_t)kr_ * L_ + ((kc_ ^ (kr_ & 7)) * 8);
    const bf16_t* gV1 = gV0 + (size_t)32 * L_;
    unsigned ldsK0 = (unsigned)(w * 1024);
    unsigned ldsK1 = (unsigned)(4096 + w * 1024);
    unsigned ldsV0 = (unsigned)(8192 + w * 1024);
    unsigned ldsV1 = (unsigned)(12288 + w * 1024);

    bf16x8 qf[4];
    #pragma unroll
    for (int c = 0; c < 4; ++c)
        qf[c] = *(const bf16x8*)(qb + lo5 * D_ + c * 16 + hi * 8);

    int kx = lo5 & 7;
    int koff0 = lo5 * 64 + (((0 | hi) ^ kx) << 3);
    int koff1 = lo5 * 64 + (((2 | hi) ^ kx) << 3);
    int koff2 = lo5 * 64 + (((4 | hi) ^ kx) << 3);
    int koff3 = lo5 * 64 + (((6 | hi) ^ kx) << 3);
    int vrow0 = 4096 + lo5 * 64;
    int vrow1 = 4096 + (lo5 + 32) * 64;
    int vb00 = ((0 | hi) ^ kx) << 3, vb01 = ((2 | hi) ^ kx) << 3;
    int vb10 = ((4 | hi) ^ kx) << 3, vb11 = ((6 | hi) ^ kx) << 3;
    int shv = hi << 2;

    f32x16 o0, o1;
    #pragma unroll
    for (int r = 0; r < 16; ++r) { o0[r] = 0.f; o1[r] = 0.f; }
    float lsum = 0.f;
    f32x16 kZero;
    #pragma unroll
    for (int r = 0; r < 16; ++r) kZero[r] = 0.f;

    auto stage = [&](int buf) {
        unsigned bb = (unsigned)buf * 16384u;
        GLOAD16(gK0, smem + bb + ldsK0);
        GLOAD16(gK1, smem + bb + ldsK1);
        GLOAD16(gV0, smem + bb + ldsV0);
        GLOAD16(gV1, smem + bb + ldsV1);
        gK0 += 64 * 64; gK1 += 64 * 64;
        gV0 += 64;      gV1 += 64;
    };

    auto sub = [&](const bf16_t* Bp, int ks, int va, int vb, unsigned int mw) {
        __builtin_amdgcn_s_setprio(1);
        f32x16 st = mfma32(*(const bf16x8*)(Bp + ks + koff0), qf[0], kZero);
        st = mfma32(*(const bf16x8*)(Bp + ks + koff1), qf[1], st);
        st = mfma32(*(const bf16x8*)(Bp + ks + koff2), qf[2], st);
        st = mfma32(*(const bf16x8*)(Bp + ks + koff3), qf[3], st);
        __builtin_amdgcn_s_setprio(0);
        bf16x8 v00 = *(const bf16x8*)(Bp + vrow0 + va);
        bf16x8 v01 = *(const bf16x8*)(Bp + vrow0 + vb);
        bf16x8 v10 = *(const bf16x8*)(Bp + vrow1 + va);
        bf16x8 v11 = *(const bf16x8*)(Bp + vrow1 + vb);
        float p[16];
        #pragma unroll
        for (int r = 0; r < 16; ++r) p[r] = __builtin_amdgcn_exp2f(st[r]);
        unsigned int mws = mw >> shv;
        #pragma unroll
        for (int r = 0; r < 16; ++r) {
            int kr = (r & 3) + 8 * (r >> 2);
            int mm = __builtin_amdgcn_sbfe(mws, kr, 1);
            p[r] = __uint_as_float(__float_as_uint(p[r]) & (unsigned int)mm);
        }
        f32x2 q01 = (f32x2){p[0], p[1]}  + (f32x2){p[2], p[3]};
        f32x2 q23 = (f32x2){p[4], p[5]}  + (f32x2){p[6], p[7]};
        f32x2 q45 = (f32x2){p[8], p[9]}  + (f32x2){p[10], p[11]};
        f32x2 q67 = (f32x2){p[12], p[13]} + (f32x2){p[14], p[15]};
        f32x2 qa = q01 + q23, qb2 = q45 + q67;
        f32x2 qc = qa + qb2;
        lsum += qc.x + qc.y;
        unsigned int w0 = pk2(p[0],  p[1]),  w1 = pk2(p[2],  p[3]);
        unsigned int w2 = pk2(p[4],  p[5]),  w3 = pk2(p[6],  p[7]);
        unsigned int w4 = pk2(p[8],  p[9]),  w5 = pk2(p[10], p[11]);
        unsigned int w6 = pk2(p[12], p[13]), w7 = pk2(p[14], p[15]);
        uint2v s02 = __builtin_amdgcn_permlane32_swap(w0, w2, false, false);
        uint2v s13 = __builtin_amdgcn_permlane32_swap(w1, w3, false, false);
        uint2v s46 = __builtin_amdgcn_permlane32_swap(w4, w6, false, false);
        uint2v s57 = __builtin_amdgcn_permlane32_swap(w5, w7, false, false);
        uint4v fa0, fa1;
        fa0.x = s02.x; fa0.y = s13.x; fa0.z = s02.y; fa0.w = s13.y;
        fa1.x = s46.x; fa1.y = s57.x; fa1.z = s46.y; fa1.w = s57.y;
        bf16x8 pa0 = __builtin_bit_cast(bf16x8, fa0);
        bf16x8 pa1 = __builtin_bit_cast(bf16x8, fa1);
        __builtin_amdgcn_s_setprio(1);
        o0 = mfma32(pa0, v00, o0);
        o1 = mfma32(pa0, v10, o1);
        o0 = mfma32(pa1, v01, o0);
        o1 = mfma32(pa1, v11, o1);
        __builtin_amdgcn_s_setprio(0);
    };

    const bf16_t* B0 = (const bf16_t*)(smem);
    const bf16_t* B1 = (const bf16_t*)(smem + 16384);

    stage(0);
    unsigned int mwa = mptr[0], mwb = mptr[L_]; mptr += 2 * L_;

    #pragma unroll 1
    for (int tt = 0; tt < 16; ++tt) {
        {
            unsigned int na = mptr[0], nb = mptr[L_]; mptr += 2 * L_;
            stage(1);
            asm volatile("s_waitcnt vmcnt(4)" ::: "memory");
            __builtin_amdgcn_s_barrier();
            __builtin_amdgcn_sched_barrier(0);
            sub(B0, 0,    vb00, vb01, mwa);
            sub(B0, 2048, vb10, vb11, mwb);
            mwa = na; mwb = nb;
            __builtin_amdgcn_s_barrier();
            __builtin_amdgcn_sched_barrier(0);
        }
        {
            unsigned int na = mptr[0], nb = mptr[L_]; mptr += 2 * L_;
            if (tt < 15) {
                stage(0);
                asm volatile("s_waitcnt vmcnt(4)" ::: "memory");
            } else {
                asm volatile("s_waitcnt vmcnt(0)" ::: "memory");
            }
            __builtin_amdgcn_s_barrier();
            __builtin_amdgcn_sched_barrier(0);
            sub(B1, 0,    vb00, vb01, mwa);
            sub(B1, 2048, vb10, vb11, mwb);
            mwa = na; mwb = nb;
            __builtin_amdgcn_s_barrier();
            __builtin_amdgcn_sched_barrier(0);
        }
    }

    float lt = lsum + __shfl_xor(lsum, 32);
    #pragma unroll
    for (int r = 0; r < 16; ++r) {
        int qr = (r & 3) + 8 * (r >> 2) + 4 * hi;
        float inv = __builtin_amdgcn_rcpf(__shfl(lt, qr));
        bf16_t* orow = aoB + ((size_t)n * L_ + q0 + qr) * E_ + h * 64;
        orow[lo5]      = (bf16_t)(o0[r] * inv);
        orow[32 + lo5] = (bf16_t)(o1[r] * inv);
    }
}

// ---------------- out GEMM: 128x128, XCD row-group pinning, A-prefetch -----
__global__ __launch_bounds__(256) void out_gemm_lds_k(
    const bf16_t* __restrict__ A, const bf16_t* __restrict__ WoB,
    const float* __restrict__ bo, float* __restrict__ Y) {
    __shared__ alignas(16) unsigned char bsm[32768];   // 2 x 16KB
    int b = blockIdx.x;
    // XCD owns a contiguous ROW-group: A panel (2MB) + full Wo (2MB) L2-fit.
    int xcd = b & 7, idx = b >> 3;
    int rt = xcd * 8 + (idx & 7);       // 8 row-tiles per XCD
    int ct = idx >> 3;                  // iterate all 8 column strips
    int tid = threadIdx.x;
    int w = tid >> 6, lane = tid & 63;
    int lo5 = lane & 31, hi = lane >> 5;
    int row0 = rt * 128, col0 = ct * 128;
    const bf16_t* arow = A + (size_t)(row0 + w * 32 + lo5) * E_ + hi * 8;

    f32x16 acc0, acc1, acc2, acc3;
    #pragma unroll
    for (int r = 0; r < 16; ++r) { acc0[r]=0.f; acc1[r]=0.f; acc2[r]=0.f; acc3[r]=0.f; }

    auto stageB = [&](int kc, int buf) {
        #pragma unroll
        for (int rr = 0; rr < 4; ++rr) {
            int g = tid + rr * 256;
            int nn = g >> 3, slot = g & 7;
            const bf16_t* src = WoB + (size_t)(col0 + nn) * E_ + kc * 64 +
                                ((slot ^ (nn & 7)) * 8);
            GLOAD16(src, bsm + (size_t)buf * 16384 + (size_t)(w * 64 + rr * 256) * 16);
        }
    };

    // prologue: stage Wo tile 0, prefetch A frags for kc=0
    stageB(0, 0);
    bf16x8 afc[4];
    #pragma unroll
    for (int c = 0; c < 4; ++c) afc[c] = *(const bf16x8*)(arow + c * 16);

    #pragma unroll 1
    for (int kc = 0; kc < 16; ++kc) {
        int cur = kc & 1;
        bf16x8 afn[4];
        if (kc < 15) {
            stageB(kc + 1, cur ^ 1);
            #pragma unroll
            for (int c = 0; c < 4; ++c)
                afn[c] = *(const bf16x8*)(arow + (kc + 1) * 64 + c * 16);
            asm volatile("s_waitcnt vmcnt(8)" ::: "memory");
        } else {
            asm volatile("s_waitcnt vmcnt(0)" ::: "memory");
        }
        __builtin_amdgcn_s_barrier();
        __builtin_amdgcn_sched_barrier(0);
        const bf16_t* Bl = (const bf16_t*)(bsm + (size_t)cur * 16384);
        #pragma unroll
        for (int c = 0; c < 4; ++c) {
            int slot = ((((c << 1) | hi) ^ (lo5 & 7)) << 3);
            bf16x8 b0 = *(const bf16x8*)(Bl + (0 * 32 + lo5) * 64 + slot);
            bf16x8 b1 = *(const bf16x8*)(Bl + (1 * 32 + lo5) * 64 + slot);
            bf16x8 b2 = *(const bf16x8*)(Bl + (2 * 32 + lo5) * 64 + slot);
            bf16x8 b3 = *(const bf16x8*)(Bl + (3 * 32 + lo5) * 64 + slot);
            __builtin_amdgcn_s_setprio(1);
            acc0 = mfma32(afc[c], b0, acc0);
            acc1 = mfma32(afc[c], b1, acc1);
            acc2 = mfma32(afc[c], b2, acc2);
            acc3 = mfma32(afc[c], b3, acc3);
            __builtin_amdgcn_s_setprio(0);
        }
        #pragma unroll
        for (int c = 0; c < 4; ++c) afc[c] = afn[c];
        __builtin_amdgcn_s_barrier();
        __builtin_amdgcn_sched_barrier(0);
    }

    #define EPI(ACC, CG)                                                     \
    {                                                                        \
        float bias = bo[col0 + (CG) * 32 + lo5];                             \
        _Pragma("unroll")                                                    \
        for (int r = 0; r < 16; ++r) {                                       \
            int qr = (r & 3) + 8 * (r >> 2) + 4 * hi;                        \
            Y[(size_t)(row0 + w * 32 + qr) * E_ + col0 + (CG) * 32 + lo5] =  \
                ACC[r] + bias;                                               \
        }                                                                    \
    }
    EPI(acc0, 0) EPI(acc1, 1) EPI(acc2, 2) EPI(acc3, 3)
    #undef EPI
}

extern "C" void kernel_launch(void* const* d_in, const int* in_sizes, int n_in,
                              void* d_out, int out_size, void* d_ws, size_t ws_size,
                              hipStream_t stream) {
    const float* values  = (const float*)d_in[0];
    const float* keys    = (const float*)d_in[1];
    const float* queries = (const float*)d_in[2];
    const int*   mask    = (const int*)  d_in[3];
    const float* Wq      = (const float*)d_in[4];
    const float* Wk      = (const float*)d_in[5];
    const float* Wv      = (const float*)d_in[6];
    const float* Wo      = (const float*)d_in[7];
    const float* bo      = (const float*)d_in[8];
    float* Y = (float*)d_out;

    const size_t SZ = (size_t)N_ * H_ * L_ * D_;  // 8388608 elements
    bf16_t* qB  = (bf16_t*)d_ws;
    bf16_t* kB  = qB + SZ;
    bf16_t* vT  = kB + SZ;
    bf16_t* aoB = vT + SZ;
    unsigned int* mpkT = (unsigned int*)(aoB + SZ);
    bf16_t* WoB = (bf16_t*)(mpkT + (size_t)N_ * 64 * L_);

    pack_cvt_k<<<4096 + 1024, 256, 0, stream>>>(mask, Wo, mpkT, WoB);
    proj_mfma_k<<<dim3(N_ * L_ / 128, H_, 3), 256, 0, stream>>>(
        queries, keys, values, Wq, Wk, Wv, qB, kB, vT);
    attn_lds_k<<<N_ * H_ * (L_ / 128), 256, 0, stream>>>(
        qB, kB, vT, mpkT, aoB);
    out_gemm_lds_k<<<(E_ / 128) * (N_ * L_ / 128), 256, 0, stream>>>(
        aoB, WoB, bo, Y);
}